// Round 8
// baseline (656.411 us; speedup 1.0000x reference)
//
#include <hip/hip_runtime.h>
#include <hip/hip_bf16.h>
#include <stdint.h>

#define C_DIM 128
#define K_DIM 27

typedef __attribute__((ext_vector_type(8))) short short8;
typedef __attribute__((ext_vector_type(4))) float f32x4;
typedef __attribute__((ext_vector_type(4))) unsigned short ushort4v;

#define VMCNT8() asm volatile("s_waitcnt vmcnt(8)" ::: "memory")
#define VMCNT6() asm volatile("s_waitcnt vmcnt(6)" ::: "memory")
#define VMCNT4() asm volatile("s_waitcnt vmcnt(4)" ::: "memory")
#define VMCNT0() asm volatile("s_waitcnt vmcnt(0)" ::: "memory")
#define LGKM0() asm volatile("s_waitcnt lgkmcnt(0)" ::: "memory")
#define BAR() __builtin_amdgcn_s_barrier()

__device__ __forceinline__ unsigned short f2bf(float f) {
  unsigned int u = __builtin_bit_cast(unsigned int, f);
  u += 0x7fffu + ((u >> 16) & 1u);   // round-to-nearest-even
  return (unsigned short)(u >> 16);
}
__device__ __forceinline__ float bf2f(unsigned short h) {
  unsigned int u = ((unsigned int)h) << 16;
  return __builtin_bit_cast(float, u);
}

__device__ __forceinline__ void async_copy16(const void* gsrc, void* ldst) {
  __builtin_amdgcn_global_load_lds(
      (const __attribute__((address_space(1))) unsigned int*)gsrc,
      (__attribute__((address_space(3))) unsigned int*)ldst, 16, 0, 0);
}

// ---- W [k][ci][co] f32 -> quarter-tiled bf16 Wt[k][q][co][cq], ci = q*32+cq ----
__global__ __launch_bounds__(256) void prep_kernel(
    const float* __restrict__ W1, const float* __restrict__ W2,
    unsigned short* __restrict__ Wt1, unsigned short* __restrict__ Wt2,
    float* __restrict__ stats, int stats_n) {
  int idx = blockIdx.x * 256 + threadIdx.x;
  const int total = K_DIM * C_DIM * C_DIM;
  if (idx < total) {
    int cq = idx & 31;
    int co = (idx >> 5) & 127;
    int q  = (idx >> 12) & 3;
    int k  = idx >> 14;
    int ci = q * 32 + cq;
    int src = (k * C_DIM + ci) * C_DIM + co;
    Wt1[idx] = f2bf(W1[src]);
    Wt2[idx] = f2bf(W2[src]);
  }
  if (idx < stats_n) stats[idx] = 0.f;
}

// ---- x f32 -> bf16 copy ----
__global__ __launch_bounds__(256) void cvt_x_kernel(
    const float* __restrict__ x, unsigned short* __restrict__ xb, int total4) {
  int i = blockIdx.x * 256 + threadIdx.x;
  if (i >= total4) return;
  f32x4 v = ((const f32x4*)x)[i];
  ushort4v u;
#pragma unroll
  for (int j = 0; j < 4; ++j) u[j] = f2bf(v[j]);
  ((ushort4v*)xb)[i] = u;
}

// ---- gathered GEMM: out[i] = sum_k src[nbr[i,k]] @ W[k], fused BN stats ----
// 256 thr (4 waves), block 128x128; wave (rg,cg) owns 64x64.
// A: gathered to LDS (4-deep ring, XOR-swizzled source + read, 3-phase
// lookahead, counted vmcnt). W: direct global->VGPR, double-buffered
// (L2-hot, each wave reads its own 64-col slice, coalesced).
// LDS 47.6 KB -> 3 blocks/CU.
template<int OUT_IS_F32>
__global__ __launch_bounds__(256, 3) void conv_kernel(
    const unsigned short* __restrict__ xb, const int* __restrict__ nbr,
    const unsigned short* __restrict__ Wt, void* __restrict__ out_v,
    float* __restrict__ stats, int N) {
  extern __shared__ __align__(16) char smem[];
  unsigned short* Abuf = (unsigned short*)smem;            // 4 x 4096 elems
  int* idx_lds = (int*)(smem + 32768);                     // 128*27 ints
  float* s_sum = (float*)(smem + 32768 + 13824);           // 128 f32
  float* s_ssum = s_sum + C_DIM;                           // 128 f32

  const int tid = threadIdx.x;
  const int wave = tid >> 6, lane = tid & 63;
  const int lr = lane & 15, lg = lane >> 4;
  const int rg = wave >> 1, cg = wave & 1;
  const int row0 = blockIdx.x * 128;

  if (tid < C_DIM) { s_sum[tid] = 0.f; s_ssum[tid] = 0.f; }

  // preload nbr indices for the block's 128 rows (coalesced), clamp OOB rows
  for (int i = tid; i < 128 * K_DIM; i += 256) {
    int r = i / K_DIM;
    int k = i - r * K_DIM;
    int rr = row0 + r; if (rr >= N) rr = N - 1;
    idx_lds[i] = nbr[(size_t)rr * K_DIM + k];
  }
  __syncthreads();

  // staging geometry: instr c covers rows wave*32 + c*16 + (lane>>2);
  // slot = lane&3; source granule = slot ^ (row&3)  (XOR swizzle)
  const int srow = lane >> 2;
  const int ssw = ((lane & 3) ^ (srow & 3)) << 3;   // element offset
  const int gr0 = wave * 32 + srow;
  const int gr1 = gr0 + 16;

  auto stage = [&](int a0i, int a1i, int q, int buf) {
    unsigned short* dst = Abuf + buf * 4096 + wave * 1024;  // wave-uniform
    async_copy16(xb + (size_t)a0i * C_DIM + q * 32 + ssw, dst);
    async_copy16(xb + (size_t)a1i * C_DIM + q * 32 + ssw, dst + 512);
  };

  // W fragment base: lane (lr,lg) holds Wt row co=cg*64+ct*16+lr, elems lg*8..
  const unsigned short* wbase = Wt + (size_t)(cg * 64 + lr) * 32 + lg * 8;
  short8 wE[4], wO[4];
  auto wload = [&](short8 (&w)[4], int p) {
    const unsigned short* wp = wbase + (size_t)p * 4096;
#pragma unroll
    for (int ct = 0; ct < 4; ++ct)
      w[ct] = *(const short8*)(wp + ct * 512);
  };

  f32x4 acc[4][4] = {};
  // A-read base: row rg*64 + rt*16 + lr, granule slot lg^(lr&3)
  const unsigned short* abase =
      Abuf + (rg * 64 + lr) * 32 + ((lg ^ (lr & 3)) << 3);

  auto compute = [&](const unsigned short* ab, const short8 (&w)[4]) {
    short8 a[4];
#pragma unroll
    for (int rt = 0; rt < 4; ++rt)
      a[rt] = *(const short8*)(ab + rt * 512);
    __builtin_amdgcn_s_setprio(1);
#pragma unroll
    for (int rt = 0; rt < 4; ++rt)
#pragma unroll
      for (int ct = 0; ct < 4; ++ct)
        acc[rt][ct] = __builtin_amdgcn_mfma_f32_16x16x32_bf16(a[rt], w[ct], acc[rt][ct], 0, 0, 0);
    __builtin_amdgcn_s_setprio(0);
  };

  // ---- prologue: queue = [S0(2), W0(4), S1(2), S2(2)]; vmcnt(8) retires S0 ----
  int gA = idx_lds[gr0 * K_DIM];
  int gB = idx_lds[gr1 * K_DIM];
  stage(gA, gB, 0, 0);       // S(0)
  wload(wE, 0);              // W(0)
  stage(gA, gB, 1, 1);       // S(1)
  stage(gA, gB, 2, 2);       // S(2)
  VMCNT8();
  BAR();

  // ---- main: 26 k-blocks of 4 phases; steady vmcnt(8) retires S(p), W(p) ----
  for (int base = 0; base < 104; base += 4) {
    const int k1 = (base >> 2) + 1;
    int hA, hB;
    // p = base (even -> wE)
    wload(wO, base + 1);
    stage(gA, gB, 3, 3);                 // S(base+3), k, q=3
    hA = idx_lds[gr0 * K_DIM + k1];
    hB = idx_lds[gr1 * K_DIM + k1];
    VMCNT8();
    compute(abase, wE);
    LGKM0(); BAR();
    // p = base+1
    wload(wE, base + 2);
    stage(hA, hB, 0, 0);                 // S(base+4), k1, q=0
    VMCNT8();
    compute(abase + 4096, wO);
    LGKM0(); BAR();
    // p = base+2
    wload(wO, base + 3);
    stage(hA, hB, 1, 1);                 // S(base+5)
    VMCNT8();
    compute(abase + 8192, wE);
    LGKM0(); BAR();
    // p = base+3
    wload(wE, base + 4);
    stage(hA, hB, 2, 2);                 // S(base+6)
    VMCNT8();
    compute(abase + 12288, wO);
    LGKM0(); BAR();
    gA = hA; gB = hB;
  }

  // ---- tail: k = 26, phases 104..107 ----
  // p=104
  wload(wO, 105);
  stage(gA, gB, 3, 3);                   // S(107)
  VMCNT8();
  compute(abase, wE);
  LGKM0(); BAR();
  // p=105
  wload(wE, 106);
  VMCNT6();
  compute(abase + 4096, wO);
  LGKM0(); BAR();
  // p=106
  wload(wO, 107);
  VMCNT4();
  compute(abase + 8192, wE);
  LGKM0(); BAR();
  // p=107
  VMCNT0();
  compute(abase + 12288, wO);

  // ---- epilogue: direct coalesced stores + fused BN stats ----
  float ps[4] = {0.f, 0.f, 0.f, 0.f}, pss[4] = {0.f, 0.f, 0.f, 0.f};
#pragma unroll
  for (int rt = 0; rt < 4; ++rt) {
#pragma unroll
    for (int j = 0; j < 4; ++j) {
      int grow = row0 + rg * 64 + rt * 16 + lg * 4 + j;
      bool ok = grow < N;
#pragma unroll
      for (int ct = 0; ct < 4; ++ct) {
        float v = acc[rt][ct][j];
        if (ok) {
          int col = cg * 64 + ct * 16 + lr;
          if (OUT_IS_F32)
            ((float*)out_v)[(size_t)grow * C_DIM + col] = v;
          else
            ((unsigned short*)out_v)[(size_t)grow * C_DIM + col] = f2bf(v);
          ps[ct] += v;
          pss[ct] += v * v;
        }
      }
    }
  }
#pragma unroll
  for (int ct = 0; ct < 4; ++ct) {
    ps[ct]  += __shfl_xor(ps[ct], 16, 64);
    ps[ct]  += __shfl_xor(ps[ct], 32, 64);
    pss[ct] += __shfl_xor(pss[ct], 16, 64);
    pss[ct] += __shfl_xor(pss[ct], 32, 64);
    if (lg == 0) {
      int col = cg * 64 + ct * 16 + lr;
      atomicAdd(&s_sum[col], ps[ct]);
      atomicAdd(&s_ssum[col], pss[ct]);
    }
  }
  __syncthreads();
  if (tid < C_DIM) {
    atomicAdd(&stats[tid], s_sum[tid]);
    atomicAdd(&stats[C_DIM + tid], s_ssum[tid]);
  }
}

// ---- stats -> scale/shift ----
__global__ void finalize_kernel(const float* __restrict__ stats,
                                const float* __restrict__ g,
                                const float* __restrict__ b,
                                float* __restrict__ sshift, float invN) {
  int c = threadIdx.x;  // blockDim = 128
  float mean = stats[c] * invN;
  float var = stats[128 + c] * invN - mean * mean;
  float sc = g[c] * rsqrtf(var + 1e-5f);
  sshift[c] = sc;
  sshift[128 + c] = b[c] - mean * sc;
}

// ---- y1 <- relu(bn(y1)) in place, bf16 ----
__global__ __launch_bounds__(256) void apply_kernel(
    unsigned short* __restrict__ y, const float* __restrict__ ss, int total8) {
  int i = blockIdx.x * 256 + threadIdx.x;
  if (i >= total8) return;
  int cb = (i * 8) & 127;
  short8 u = ((short8*)y)[i];
#pragma unroll
  for (int j = 0; j < 8; ++j) {
    float f = bf2f((unsigned short)u[j]) * ss[cb + j] + ss[128 + cb + j];
    u[j] = (short)f2bf(fmaxf(f, 0.f));
  }
  ((short8*)y)[i] = u;
}

// ---- out <- relu(bn(y2) + x) in place (f32) ----
__global__ __launch_bounds__(256) void final_kernel(
    float* __restrict__ y2, const float* __restrict__ x,
    const float* __restrict__ ss, int total4) {
  int i = blockIdx.x * 256 + threadIdx.x;
  if (i >= total4) return;
  int cb = (i * 4) & 127;
  f32x4 v = ((const f32x4*)y2)[i];
  f32x4 xv = ((const f32x4*)x)[i];
#pragma unroll
  for (int j = 0; j < 4; ++j)
    v[j] = fmaxf(v[j] * ss[cb + j] + ss[128 + cb + j] + xv[j], 0.f);
  ((f32x4*)y2)[i] = v;
}

extern "C" void kernel_launch(void* const* d_in, const int* in_sizes, int n_in,
                              void* d_out, int out_size, void* d_ws, size_t ws_size,
                              hipStream_t stream) {
  const float* x  = (const float*)d_in[0];
  const int* nbr  = (const int*)d_in[1];
  const float* W1 = (const float*)d_in[2];
  const float* g1 = (const float*)d_in[3];
  const float* b1 = (const float*)d_in[4];
  const float* W2 = (const float*)d_in[5];
  const float* g2 = (const float*)d_in[6];
  const float* b2 = (const float*)d_in[7];
  float* out = (float*)d_out;

  const int N = in_sizes[0] / C_DIM;
  const int totalW = K_DIM * C_DIM * C_DIM;
  const int SMEM_BYTES = 32768 + 13824 + 1024;   // 47616 -> 3 blocks/CU

  char* ws = (char*)d_ws;
  size_t off = 0;
  auto alloc = [&](size_t bytes) {
    void* p = ws + off;
    off = (off + bytes + 255) & ~(size_t)255;
    return p;
  };
  unsigned short* Wt1 = (unsigned short*)alloc((size_t)totalW * 2);
  unsigned short* Wt2 = (unsigned short*)alloc((size_t)totalW * 2);
  float* stats = (float*)alloc(512 * 4);   // [0:256) conv1, [256:512) conv2
  float* ss1   = (float*)alloc(256 * 4);
  float* ss2   = (float*)alloc(256 * 4);
  unsigned short* y1 = (unsigned short*)alloc((size_t)N * C_DIM * 2);
  unsigned short* xb_ws = (unsigned short*)alloc((size_t)N * C_DIM * 2);
  // fall back to d_out's storage for the bf16 x copy if ws is too small
  unsigned short* xb = (off <= ws_size) ? xb_ws : (unsigned short*)d_out;

  const int nblk = (N + 127) / 128;
  const float invN = 1.0f / (float)N;

  prep_kernel<<<(totalW + 255) / 256, 256, 0, stream>>>(W1, W2, Wt1, Wt2, stats, 512);

  {
    int t4 = N * C_DIM / 4;
    cvt_x_kernel<<<(t4 + 255) / 256, 256, 0, stream>>>(x, xb, t4);
  }

  conv_kernel<0><<<nblk, 256, SMEM_BYTES, stream>>>(xb, nbr, Wt1, y1, stats, N);
  finalize_kernel<<<1, 128, 0, stream>>>(stats, g1, b1, ss1, invN);

  {
    int t8 = N * C_DIM / 8;
    apply_kernel<<<(t8 + 255) / 256, 256, 0, stream>>>(y1, ss1, t8);
  }

  conv_kernel<1><<<nblk, 256, SMEM_BYTES, stream>>>(y1, nbr, Wt2, out, stats + 256, N);
  finalize_kernel<<<1, 128, 0, stream>>>(stats + 256, g2, b2, ss2, invN);

  {
    int t4 = N * C_DIM / 4;
    final_kernel<<<(t4 + 255) / 256, 256, 0, stream>>>(out, x, ss2, t4);
  }
}

// Round 9
// 651.980 us; speedup vs baseline: 1.0068x; 1.0068x over previous
//
#include <hip/hip_runtime.h>
#include <hip/hip_bf16.h>
#include <stdint.h>

#define C_DIM 128
#define K_DIM 27

typedef __attribute__((ext_vector_type(8))) short short8;
typedef __attribute__((ext_vector_type(4))) float f32x4;
typedef __attribute__((ext_vector_type(4))) unsigned short ushort4v;

#define FENCE() asm volatile("" ::: "memory")
#define VMCNT12() asm volatile("s_waitcnt vmcnt(12)" ::: "memory")
#define VMCNT10() asm volatile("s_waitcnt vmcnt(10)" ::: "memory")
#define VMCNT4()  asm volatile("s_waitcnt vmcnt(4)" ::: "memory")
#define VMCNT0()  asm volatile("s_waitcnt vmcnt(0)" ::: "memory")
#define LGKM0() asm volatile("s_waitcnt lgkmcnt(0)" ::: "memory")
#define BAR() __builtin_amdgcn_s_barrier()

__device__ __forceinline__ unsigned short f2bf(float f) {
  unsigned int u = __builtin_bit_cast(unsigned int, f);
  u += 0x7fffu + ((u >> 16) & 1u);   // round-to-nearest-even
  return (unsigned short)(u >> 16);
}
__device__ __forceinline__ float bf2f(unsigned short h) {
  unsigned int u = ((unsigned int)h) << 16;
  return __builtin_bit_cast(float, u);
}

__device__ __forceinline__ void async_copy16(const void* gsrc, void* ldst) {
  __builtin_amdgcn_global_load_lds(
      (const __attribute__((address_space(1))) unsigned int*)gsrc,
      (__attribute__((address_space(3))) unsigned int*)ldst, 16, 0, 0);
}

// ---- W [k][ci][co] f32 -> quarter-tiled bf16 Wt[k][q][co][cq], ci = q*32+cq ----
__global__ __launch_bounds__(256) void prep_kernel(
    const float* __restrict__ W1, const float* __restrict__ W2,
    unsigned short* __restrict__ Wt1, unsigned short* __restrict__ Wt2,
    float* __restrict__ stats, int stats_n) {
  int idx = blockIdx.x * 256 + threadIdx.x;
  const int total = K_DIM * C_DIM * C_DIM;
  if (idx < total) {
    int cq = idx & 31;
    int co = (idx >> 5) & 127;
    int q  = (idx >> 12) & 3;
    int k  = idx >> 14;
    int ci = q * 32 + cq;
    int src = (k * C_DIM + ci) * C_DIM + co;
    Wt1[idx] = f2bf(W1[src]);
    Wt2[idx] = f2bf(W2[src]);
  }
  if (idx < stats_n) stats[idx] = 0.f;
}

// ---- x f32 -> bf16 copy ----
__global__ __launch_bounds__(256) void cvt_x_kernel(
    const float* __restrict__ x, unsigned short* __restrict__ xb, int total4) {
  int i = blockIdx.x * 256 + threadIdx.x;
  if (i >= total4) return;
  f32x4 v = ((const f32x4*)x)[i];
  ushort4v u;
#pragma unroll
  for (int j = 0; j < 4; ++j) u[j] = f2bf(v[j]);
  ((ushort4v*)xb)[i] = u;
}

// ---- gathered GEMM: out[i] = sum_k src[nbr[i,k]] @ W[k], fused BN stats ----
// 256 thr (4 waves), block 128x128; wave (rg,cg) owns 64x64.
// A: gathered to LDS 4-deep ring, lookahead 3, swizzle slot^((row>>1)&3)
//   (row stride 64B = 16 banks -> bank-set (row&1, granule); the >>1 XOR
//    gives uniform 8 lanes per bank-set = conflict-free b128 reads).
// W: global->VGPR, 4 rotating buffers, lookahead 2 (compile-time indices).
// Ledger: J(p) = [S(p+3) x2, W(p+2) x4]; steady vmcnt(12) retires
// [S(p+1), W(p)]. Tail 12/10/4/0. LDS 47.6 KB -> 3 blocks/CU.
template<int OUT_IS_F32>
__global__ __launch_bounds__(256, 3) void conv_kernel(
    const unsigned short* __restrict__ xb, const int* __restrict__ nbr,
    const unsigned short* __restrict__ Wt, void* __restrict__ out_v,
    float* __restrict__ stats, int N) {
  extern __shared__ __align__(16) char smem[];
  unsigned short* Abuf = (unsigned short*)smem;            // 4 x 4096 elems
  int* idx_lds = (int*)(smem + 32768);                     // 128*27 ints
  float* s_sum = (float*)(smem + 32768 + 13824);           // 128 f32
  float* s_ssum = s_sum + C_DIM;                           // 128 f32

  const int tid = threadIdx.x;
  const int wave = tid >> 6, lane = tid & 63;
  const int lr = lane & 15, lg = lane >> 4;
  const int rg = wave >> 1, cg = wave & 1;
  const int row0 = blockIdx.x * 128;

  if (tid < C_DIM) { s_sum[tid] = 0.f; s_ssum[tid] = 0.f; }

  // preload nbr indices for the block's 128 rows (coalesced), clamp OOB rows
  for (int i = tid; i < 128 * K_DIM; i += 256) {
    int r = i / K_DIM;
    int k = i - r * K_DIM;
    int rr = row0 + r; if (rr >= N) rr = N - 1;
    idx_lds[i] = nbr[(size_t)rr * K_DIM + k];
  }
  __syncthreads();

  // staging: lane -> local row srow = lane>>2 (two instrs: srow, srow+16),
  // slot = lane&3; source granule = slot ^ ((srow>>1)&3)
  const int ssw = ((lane & 3) ^ ((lane >> 3) & 3)) << 3;  // elem offset
  const int gr0 = wave * 32 + (lane >> 2);
  const int gr1 = gr0 + 16;

  auto stage = [&](int a0i, int a1i, int q, int buf) {
    unsigned short* dst = Abuf + buf * 4096 + wave * 1024;  // wave-uniform
    async_copy16(xb + (size_t)a0i * C_DIM + q * 32 + ssw, dst);
    async_copy16(xb + (size_t)a1i * C_DIM + q * 32 + ssw, dst + 512);
  };

  // W fragment: lane (lr,lg) holds Wt row co=cg*64+ct*16+lr, elems lg*8..
  const unsigned short* wbase = Wt + (size_t)(cg * 64 + lr) * 32 + lg * 8;
  short8 w0[4], w1[4], w2[4], w3[4];
#define WLOAD(W, P)                                                      \
  do {                                                                   \
    const unsigned short* wp_ = wbase + (size_t)(P) * 4096;              \
    _Pragma("unroll")                                                    \
    for (int ct = 0; ct < 4; ++ct) W[ct] = *(const short8*)(wp_ + ct * 512); \
  } while (0)

  f32x4 acc[4][4] = {};
  // A-read: row = rg*64 + rt*16 + lr, slot = lg ^ ((lr>>1)&3)
  const unsigned short* abase =
      Abuf + (rg * 64 + lr) * 32 + ((lg ^ ((lr >> 1) & 3)) << 3);

#define COMPUTE(BUFOFS, W)                                               \
  do {                                                                   \
    short8 a_[4];                                                        \
    _Pragma("unroll")                                                    \
    for (int rt = 0; rt < 4; ++rt)                                       \
      a_[rt] = *(const short8*)(abase + (BUFOFS) + rt * 512);            \
    __builtin_amdgcn_s_setprio(1);                                       \
    _Pragma("unroll")                                                    \
    for (int rt = 0; rt < 4; ++rt)                                       \
      _Pragma("unroll")                                                  \
      for (int ct = 0; ct < 4; ++ct)                                     \
        acc[rt][ct] = __builtin_amdgcn_mfma_f32_16x16x32_bf16(           \
            a_[rt], W[ct], acc[rt][ct], 0, 0, 0);                        \
    __builtin_amdgcn_s_setprio(0);                                       \
  } while (0)

  // ---- prologue: queue = [S0,S1,W0,S2,W1] = 14; retire S0 -> 12 ----
  int gA = idx_lds[gr0 * K_DIM];
  int gB = idx_lds[gr1 * K_DIM];
  stage(gA, gB, 0, 0); FENCE();
  stage(gA, gB, 1, 1); FENCE();
  WLOAD(w0, 0); FENCE();
  stage(gA, gB, 2, 2); FENCE();
  WLOAD(w1, 1); FENCE();
  VMCNT12();
  BAR();

  // ---- main: 26 k-blocks x 4 phases (p = 0..103) ----
  for (int base = 0; base < 104; base += 4) {
    const int k1 = (base >> 2) + 1;
    int hA, hB;
    // u=0: p=base. J = [S(base+3) buf3 (k,q3,g), W(base+2)->w2]
    stage(gA, gB, 3, 3); FENCE();
    WLOAD(w2, base + 2); FENCE();
    hA = idx_lds[gr0 * K_DIM + k1];
    hB = idx_lds[gr1 * K_DIM + k1];
    VMCNT12();
    COMPUTE(0, w0);
    LGKM0(); BAR();
    // u=1: p=base+1. J = [S(base+4) buf0 (k1,q0,h), W(base+3)->w3]
    stage(hA, hB, 0, 0); FENCE();
    WLOAD(w3, base + 3); FENCE();
    VMCNT12();
    COMPUTE(4096, w1);
    LGKM0(); BAR();
    // u=2: p=base+2. J = [S(base+5) buf1 (k1,q1,h), W(base+4)->w0]
    stage(hA, hB, 1, 1); FENCE();
    WLOAD(w0, base + 4); FENCE();
    VMCNT12();
    COMPUTE(8192, w2);
    LGKM0(); BAR();
    // u=3: p=base+3. J = [S(base+6) buf2 (k1,q2,h), W(base+5)->w1]
    stage(hA, hB, 2, 2); FENCE();
    WLOAD(w1, base + 5); FENCE();
    VMCNT12();
    COMPUTE(12288, w3);
    LGKM0(); BAR();
    gA = hA; gB = hB;
  }

  // ---- tail: phases 104..107 (k = 26) ----
  // p=104: J = [S(107) buf3 (q3), W(106)->w2]
  stage(gA, gB, 3, 3); FENCE();
  WLOAD(w2, 106); FENCE();
  VMCNT12();
  COMPUTE(0, w0);
  LGKM0(); BAR();
  // p=105: J = [W(107)->w3]
  WLOAD(w3, 107); FENCE();
  VMCNT10();
  COMPUTE(4096, w1);
  LGKM0(); BAR();
  // p=106
  VMCNT4();
  COMPUTE(8192, w2);
  LGKM0(); BAR();
  // p=107
  VMCNT0();
  COMPUTE(12288, w3);
#undef WLOAD
#undef COMPUTE

  // ---- epilogue: direct coalesced stores + fused BN stats ----
  float ps[4] = {0.f, 0.f, 0.f, 0.f}, pss[4] = {0.f, 0.f, 0.f, 0.f};
#pragma unroll
  for (int rt = 0; rt < 4; ++rt) {
#pragma unroll
    for (int j = 0; j < 4; ++j) {
      int grow = row0 + rg * 64 + rt * 16 + lg * 4 + j;
      bool ok = grow < N;
#pragma unroll
      for (int ct = 0; ct < 4; ++ct) {
        float v = acc[rt][ct][j];
        if (ok) {
          int col = cg * 64 + ct * 16 + lr;
          if (OUT_IS_F32)
            ((float*)out_v)[(size_t)grow * C_DIM + col] = v;
          else
            ((unsigned short*)out_v)[(size_t)grow * C_DIM + col] = f2bf(v);
          ps[ct] += v;
          pss[ct] += v * v;
        }
      }
    }
  }
#pragma unroll
  for (int ct = 0; ct < 4; ++ct) {
    ps[ct]  += __shfl_xor(ps[ct], 16, 64);
    ps[ct]  += __shfl_xor(ps[ct], 32, 64);
    pss[ct] += __shfl_xor(pss[ct], 16, 64);
    pss[ct] += __shfl_xor(pss[ct], 32, 64);
    if (lg == 0) {
      int col = cg * 64 + ct * 16 + lr;
      atomicAdd(&s_sum[col], ps[ct]);
      atomicAdd(&s_ssum[col], pss[ct]);
    }
  }
  __syncthreads();
  if (tid < C_DIM) {
    atomicAdd(&stats[tid], s_sum[tid]);
    atomicAdd(&stats[C_DIM + tid], s_ssum[tid]);
  }
}

// ---- stats -> scale/shift ----
__global__ void finalize_kernel(const float* __restrict__ stats,
                                const float* __restrict__ g,
                                const float* __restrict__ b,
                                float* __restrict__ sshift, float invN) {
  int c = threadIdx.x;  // blockDim = 128
  float mean = stats[c] * invN;
  float var = stats[128 + c] * invN - mean * mean;
  float sc = g[c] * rsqrtf(var + 1e-5f);
  sshift[c] = sc;
  sshift[128 + c] = b[c] - mean * sc;
}

// ---- y1 <- relu(bn(y1)) in place, bf16 ----
__global__ __launch_bounds__(256) void apply_kernel(
    unsigned short* __restrict__ y, const float* __restrict__ ss, int total8) {
  int i = blockIdx.x * 256 + threadIdx.x;
  if (i >= total8) return;
  int cb = (i * 8) & 127;
  short8 u = ((short8*)y)[i];
#pragma unroll
  for (int j = 0; j < 8; ++j) {
    float f = bf2f((unsigned short)u[j]) * ss[cb + j] + ss[128 + cb + j];
    u[j] = (short)f2bf(fmaxf(f, 0.f));
  }
  ((short8*)y)[i] = u;
}

// ---- out <- relu(bn(y2) + x) in place (f32) ----
__global__ __launch_bounds__(256) void final_kernel(
    float* __restrict__ y2, const float* __restrict__ x,
    const float* __restrict__ ss, int total4) {
  int i = blockIdx.x * 256 + threadIdx.x;
  if (i >= total4) return;
  int cb = (i * 4) & 127;
  f32x4 v = ((const f32x4*)y2)[i];
  f32x4 xv = ((const f32x4*)x)[i];
#pragma unroll
  for (int j = 0; j < 4; ++j)
    v[j] = fmaxf(v[j] * ss[cb + j] + ss[128 + cb + j] + xv[j], 0.f);
  ((f32x4*)y2)[i] = v;
}

extern "C" void kernel_launch(void* const* d_in, const int* in_sizes, int n_in,
                              void* d_out, int out_size, void* d_ws, size_t ws_size,
                              hipStream_t stream) {
  const float* x  = (const float*)d_in[0];
  const int* nbr  = (const int*)d_in[1];
  const float* W1 = (const float*)d_in[2];
  const float* g1 = (const float*)d_in[3];
  const float* b1 = (const float*)d_in[4];
  const float* W2 = (const float*)d_in[5];
  const float* g2 = (const float*)d_in[6];
  const float* b2 = (const float*)d_in[7];
  float* out = (float*)d_out;

  const int N = in_sizes[0] / C_DIM;
  const int totalW = K_DIM * C_DIM * C_DIM;
  const int SMEM_BYTES = 32768 + 13824 + 1024;   // 47616 -> 3 blocks/CU

  char* ws = (char*)d_ws;
  size_t off = 0;
  auto alloc = [&](size_t bytes) {
    void* p = ws + off;
    off = (off + bytes + 255) & ~(size_t)255;
    return p;
  };
  unsigned short* Wt1 = (unsigned short*)alloc((size_t)totalW * 2);
  unsigned short* Wt2 = (unsigned short*)alloc((size_t)totalW * 2);
  float* stats = (float*)alloc(512 * 4);   // [0:256) conv1, [256:512) conv2
  float* ss1   = (float*)alloc(256 * 4);
  float* ss2   = (float*)alloc(256 * 4);
  unsigned short* y1 = (unsigned short*)alloc((size_t)N * C_DIM * 2);
  unsigned short* xb_ws = (unsigned short*)alloc((size_t)N * C_DIM * 2);
  // fall back to d_out's storage for the bf16 x copy if ws is too small
  unsigned short* xb = (off <= ws_size) ? xb_ws : (unsigned short*)d_out;

  const int nblk = (N + 127) / 128;
  const float invN = 1.0f / (float)N;

  prep_kernel<<<(totalW + 255) / 256, 256, 0, stream>>>(W1, W2, Wt1, Wt2, stats, 512);

  {
    int t4 = N * C_DIM / 4;
    cvt_x_kernel<<<(t4 + 255) / 256, 256, 0, stream>>>(x, xb, t4);
  }

  conv_kernel<0><<<nblk, 256, SMEM_BYTES, stream>>>(xb, nbr, Wt1, y1, stats, N);
  finalize_kernel<<<1, 128, 0, stream>>>(stats, g1, b1, ss1, invN);

  {
    int t8 = N * C_DIM / 8;
    apply_kernel<<<(t8 + 255) / 256, 256, 0, stream>>>(y1, ss1, t8);
  }

  conv_kernel<1><<<nblk, 256, SMEM_BYTES, stream>>>(y1, nbr, Wt2, out, stats + 256, N);
  finalize_kernel<<<1, 128, 0, stream>>>(stats + 256, g2, b2, ss2, invN);

  {
    int t4 = N * C_DIM / 4;
    final_kernel<<<(t4 + 255) / 256, 256, 0, stream>>>(out, x, ss2, t4);
  }
}

// Round 10
// 600.091 us; speedup vs baseline: 1.0939x; 1.0865x over previous
//
#include <hip/hip_runtime.h>
#include <hip/hip_bf16.h>
#include <stdint.h>

#define C_DIM 128
#define K_DIM 27

typedef __attribute__((ext_vector_type(8))) short short8;
typedef __attribute__((ext_vector_type(4))) float f32x4;
typedef __attribute__((ext_vector_type(4))) unsigned short ushort4v;

#define VMCNT5() asm volatile("s_waitcnt vmcnt(5)" ::: "memory")
#define VMCNT3() asm volatile("s_waitcnt vmcnt(3)" ::: "memory")
#define VMCNT0() asm volatile("s_waitcnt vmcnt(0)" ::: "memory")
#define LGKM0() asm volatile("s_waitcnt lgkmcnt(0)" ::: "memory")
#define BAR() __builtin_amdgcn_s_barrier()

__device__ __forceinline__ unsigned short f2bf(float f) {
  unsigned int u = __builtin_bit_cast(unsigned int, f);
  u += 0x7fffu + ((u >> 16) & 1u);   // round-to-nearest-even
  return (unsigned short)(u >> 16);
}
__device__ __forceinline__ float bf2f(unsigned short h) {
  unsigned int u = ((unsigned int)h) << 16;
  return __builtin_bit_cast(float, u);
}

__device__ __forceinline__ void async_copy16(const void* gsrc, void* ldst) {
  __builtin_amdgcn_global_load_lds(
      (const __attribute__((address_space(1))) unsigned int*)gsrc,
      (__attribute__((address_space(3))) unsigned int*)ldst, 16, 0, 0);
}

// ---- W [k][ci][co] f32 -> phase-tiled swizzled bf16
// Wt[p][co][gpos][e], p = k*4+q, logical ci = q*32 + (gpos^((co>>1)&3))*8 + e
__global__ __launch_bounds__(256) void prep_kernel(
    const float* __restrict__ W1, const float* __restrict__ W2,
    unsigned short* __restrict__ Wt1, unsigned short* __restrict__ Wt2,
    float* __restrict__ stats, int stats_n) {
  int idx = blockIdx.x * 256 + threadIdx.x;
  const int total = K_DIM * C_DIM * C_DIM;
  if (idx < total) {
    int e = idx & 7;
    int gpos = (idx >> 3) & 3;
    int co = (idx >> 5) & 127;
    int p = idx >> 12;
    int k = p >> 2, q = p & 3;
    int ci = q * 32 + ((gpos ^ ((co >> 1) & 3)) << 3) + e;
    int src = (k * C_DIM + ci) * C_DIM + co;
    Wt1[idx] = f2bf(W1[src]);
    Wt2[idx] = f2bf(W2[src]);
  }
  if (idx < stats_n) stats[idx] = 0.f;
}

// ---- nbr [N][27] -> nbrT [27][N] (LDS-tiled transpose, both sides coalesced) ----
__global__ __launch_bounds__(256) void tr_kernel(
    const int* __restrict__ nbr, int* __restrict__ nbrT, int N) {
  __shared__ int t[64 * K_DIM];
  const int row0 = blockIdx.x * 64;
  for (int i = threadIdx.x; i < 64 * K_DIM; i += 256) {
    int r = i / K_DIM, kk = i - r * K_DIM;
    int rr = row0 + r;
    t[kk * 64 + r] = (rr < N) ? nbr[(size_t)rr * K_DIM + kk] : 0;
  }
  __syncthreads();
  for (int j = threadIdx.x; j < K_DIM * 64; j += 256) {
    int kk = j >> 6, r = j & 63;
    if (row0 + r < N) nbrT[(size_t)kk * N + row0 + r] = t[j];
  }
}

// ---- x f32 -> bf16 copy ----
__global__ __launch_bounds__(256) void cvt_x_kernel(
    const float* __restrict__ x, unsigned short* __restrict__ xb, int total4) {
  int i = blockIdx.x * 256 + threadIdx.x;
  if (i >= total4) return;
  f32x4 v = ((const f32x4*)x)[i];
  ushort4v u;
#pragma unroll
  for (int j = 0; j < 4; ++j) u[j] = f2bf(v[j]);
  ((ushort4v*)xb)[i] = u;
}

// ---- gathered GEMM: out[i] = sum_k src[nbr[i,k]] @ W[k], fused BN stats ----
// 512 thr (8 waves), block 256 rows x 128 cols; wave (rg=w>>1, cg=w&1) owns 64x64.
// 108 quarter-k phases (32 ci each). A (16 KB) and W (8 KB) phase tiles both in
// 3-deep LDS rings, DMA-staged with lookahead 2; XOR swizzle slot^((row>>1)&3)
// on source + read (R9-proven, 0 conflicts). gather indices from nbrT as 64 B
// coalesced VGPR loads, prefetched 1 k ahead. Invariant entering phase p: all
// waves' S(p) landed (prev phase's vmcnt + barrier). Pre-barrier waits drain
// S(p+1): q-pattern 5/5/3/3; never 0 in main loop. 73 KB LDS -> 2 blocks/CU.
template<int OUT_IS_F32>
__global__ __launch_bounds__(512, 4) void conv_kernel(
    const unsigned short* __restrict__ xb, const int* __restrict__ nbrT,
    const unsigned short* __restrict__ Wt, void* __restrict__ out_v,
    float* __restrict__ stats, int N) {
  extern __shared__ __align__(16) char smem[];
  unsigned short* Abuf = (unsigned short*)smem;            // 3 x 8192 elems
  unsigned short* Wbuf = (unsigned short*)(smem + 49152);  // 3 x 4096 elems
  float* s_sum = (float*)(smem + 73728);                   // 128 f32
  float* s_ssum = s_sum + C_DIM;                           // 128 f32

  const int tid = threadIdx.x;
  const int wave = tid >> 6, lane = tid & 63;
  const int lr = lane & 15, lg = lane >> 4;
  const int rg = wave >> 1, cg = wave & 1;
  const int row0 = blockIdx.x * 256;

  if (tid < C_DIM) { s_sum[tid] = 0.f; s_ssum[tid] = 0.f; }

  // staging geometry: instr c covers rows wave*32 + c*16 + srow, srow = lane>>2;
  // source granule = (lane&3) ^ ((srow>>1)&3); LDS stays linear.
  const int srow = lane >> 2;
  const int ssw = ((lane & 3) ^ ((srow >> 1) & 3)) << 3;   // elem offset
  int rA = row0 + wave * 32 + srow;      if (rA >= N) rA = N - 1;
  int rB = row0 + wave * 32 + 16 + srow; if (rB >= N) rB = N - 1;

  auto stage_a = [&](int giA, int giB, int q, int aofs) {
    unsigned short* dst = Abuf + aofs + wave * 1024;   // wave-uniform base
    async_copy16(xb + (size_t)giA * C_DIM + q * 32 + ssw, dst);
    async_copy16(xb + (size_t)giB * C_DIM + q * 32 + ssw, dst + 512);
  };
  auto stage_w = [&](const unsigned short* wsrc, int wofs) {
    async_copy16(wsrc + wave * 512 + lane * 8, Wbuf + wofs + wave * 512);
  };

  f32x4 acc[4][4] = {};
  const int swzr = (lg ^ ((lr >> 1) & 3)) << 3;
  const int aro = (rg * 64 + lr) * 32 + swzr;
  const int wro = (cg * 64 + lr) * 32 + swzr;

  auto compute = [&](int cAo, int cWo) {
    short8 a_[4], b_[4];
#pragma unroll
    for (int rt = 0; rt < 4; ++rt)
      a_[rt] = *(const short8*)(Abuf + cAo + aro + rt * 512);
#pragma unroll
    for (int ct = 0; ct < 4; ++ct)
      b_[ct] = *(const short8*)(Wbuf + cWo + wro + ct * 512);
    __builtin_amdgcn_s_setprio(1);
#pragma unroll
    for (int rt = 0; rt < 4; ++rt)
#pragma unroll
      for (int ct = 0; ct < 4; ++ct)
        acc[rt][ct] = __builtin_amdgcn_mfma_f32_16x16x32_bf16(
            a_[rt], b_[ct], acc[rt][ct], 0, 0, 0);
    __builtin_amdgcn_s_setprio(0);
  };

  // ---- prologue: gi(0); stage S(0) slot0, S(1) slot1; drain S(0); barrier ----
  int giA = nbrT[rA];
  int giB = nbrT[rB];
  stage_a(giA, giB, 0, 0);     stage_w(Wt, 0);          // S(0)
  stage_a(giA, giB, 1, 8192);  stage_w(Wt + 4096, 4096);// S(1)
  VMCNT3();    // S(0) landed (own); barrier publishes across waves
  BAR();

  const unsigned short* wsrc = Wt + 2 * 4096;
  int cAo = 0, cWo = 0, sAo = 16384, sWo = 8192;
  int giNA, giNB;

#define ADV() do {                                   \
    cAo = (cAo == 16384) ? 0 : cAo + 8192;           \
    sAo = (sAo == 16384) ? 0 : sAo + 8192;           \
    cWo = (cWo == 8192) ? 0 : cWo + 4096;            \
    sWo = (sWo == 8192) ? 0 : sWo + 4096;            \
  } while (0)

  // ---- main: k = 0..25, 4 phases each ----
  for (int k = 0; k < K_DIM - 1; ++k) {
    // q0: stage (k,q2) with giC; prefetch gi(k+1)
    stage_a(giA, giB, 2, sAo); stage_w(wsrc, sWo); wsrc += 4096;
    giNA = nbrT[(size_t)(k + 1) * N + rA];
    giNB = nbrT[(size_t)(k + 1) * N + rB];
    compute(cAo, cWo);
    VMCNT5(); LGKM0(); BAR(); ADV();
    // q1: stage (k,q3)
    stage_a(giA, giB, 3, sAo); stage_w(wsrc, sWo); wsrc += 4096;
    compute(cAo, cWo);
    VMCNT5(); LGKM0(); BAR(); ADV();
    // q2: stage (k+1,q0) with giN
    stage_a(giNA, giNB, 0, sAo); stage_w(wsrc, sWo); wsrc += 4096;
    compute(cAo, cWo);
    VMCNT3(); LGKM0(); BAR(); ADV();
    // q3: stage (k+1,q1)
    stage_a(giNA, giNB, 1, sAo); stage_w(wsrc, sWo); wsrc += 4096;
    compute(cAo, cWo);
    VMCNT3(); LGKM0(); BAR(); ADV();
    giA = giNA; giB = giNB;
  }

  // ---- tail: k = 26, phases 104..107 ----
  stage_a(giA, giB, 2, sAo); stage_w(wsrc, sWo); wsrc += 4096;
  compute(cAo, cWo);
  VMCNT3(); LGKM0(); BAR(); ADV();
  stage_a(giA, giB, 3, sAo); stage_w(wsrc, sWo);
  compute(cAo, cWo);
  VMCNT3(); LGKM0(); BAR(); ADV();
  compute(cAo, cWo);
  VMCNT0(); LGKM0(); BAR(); ADV();
  compute(cAo, cWo);
#undef ADV

  // ---- epilogue: direct coalesced stores + fused BN stats ----
  float ps[4] = {0.f, 0.f, 0.f, 0.f}, pss[4] = {0.f, 0.f, 0.f, 0.f};
#pragma unroll
  for (int rt = 0; rt < 4; ++rt) {
#pragma unroll
    for (int j = 0; j < 4; ++j) {
      int grow = row0 + rg * 64 + rt * 16 + lg * 4 + j;
      bool ok = grow < N;
#pragma unroll
      for (int ct = 0; ct < 4; ++ct) {
        float v = acc[rt][ct][j];
        if (ok) {
          int col = cg * 64 + ct * 16 + lr;
          if (OUT_IS_F32)
            ((float*)out_v)[(size_t)grow * C_DIM + col] = v;
          else
            ((unsigned short*)out_v)[(size_t)grow * C_DIM + col] = f2bf(v);
          ps[ct] += v;
          pss[ct] += v * v;
        }
      }
    }
  }
#pragma unroll
  for (int ct = 0; ct < 4; ++ct) {
    ps[ct]  += __shfl_xor(ps[ct], 16, 64);
    ps[ct]  += __shfl_xor(ps[ct], 32, 64);
    pss[ct] += __shfl_xor(pss[ct], 16, 64);
    pss[ct] += __shfl_xor(pss[ct], 32, 64);
    if (lg == 0) {
      int col = cg * 64 + ct * 16 + lr;
      atomicAdd(&s_sum[col], ps[ct]);
      atomicAdd(&s_ssum[col], pss[ct]);
    }
  }
  __syncthreads();
  if (tid < C_DIM) {
    atomicAdd(&stats[tid], s_sum[tid]);
    atomicAdd(&stats[C_DIM + tid], s_ssum[tid]);
  }
}

// ---- stats -> scale/shift ----
__global__ void finalize_kernel(const float* __restrict__ stats,
                                const float* __restrict__ g,
                                const float* __restrict__ b,
                                float* __restrict__ sshift, float invN) {
  int c = threadIdx.x;  // blockDim = 128
  float mean = stats[c] * invN;
  float var = stats[128 + c] * invN - mean * mean;
  float sc = g[c] * rsqrtf(var + 1e-5f);
  sshift[c] = sc;
  sshift[128 + c] = b[c] - mean * sc;
}

// ---- y1 <- relu(bn(y1)) in place, bf16 ----
__global__ __launch_bounds__(256) void apply_kernel(
    unsigned short* __restrict__ y, const float* __restrict__ ss, int total8) {
  int i = blockIdx.x * 256 + threadIdx.x;
  if (i >= total8) return;
  int cb = (i * 8) & 127;
  short8 u = ((short8*)y)[i];
#pragma unroll
  for (int j = 0; j < 8; ++j) {
    float f = bf2f((unsigned short)u[j]) * ss[cb + j] + ss[128 + cb + j];
    u[j] = (short)f2bf(fmaxf(f, 0.f));
  }
  ((short8*)y)[i] = u;
}

// ---- out <- relu(bn(y2) + x) in place (f32) ----
__global__ __launch_bounds__(256) void final_kernel(
    float* __restrict__ y2, const float* __restrict__ x,
    const float* __restrict__ ss, int total4) {
  int i = blockIdx.x * 256 + threadIdx.x;
  if (i >= total4) return;
  int cb = (i * 4) & 127;
  f32x4 v = ((const f32x4*)y2)[i];
  f32x4 xv = ((const f32x4*)x)[i];
#pragma unroll
  for (int j = 0; j < 4; ++j)
    v[j] = fmaxf(v[j] * ss[cb + j] + ss[128 + cb + j] + xv[j], 0.f);
  ((f32x4*)y2)[i] = v;
}

extern "C" void kernel_launch(void* const* d_in, const int* in_sizes, int n_in,
                              void* d_out, int out_size, void* d_ws, size_t ws_size,
                              hipStream_t stream) {
  const float* x  = (const float*)d_in[0];
  const int* nbr  = (const int*)d_in[1];
  const float* W1 = (const float*)d_in[2];
  const float* g1 = (const float*)d_in[3];
  const float* b1 = (const float*)d_in[4];
  const float* W2 = (const float*)d_in[5];
  const float* g2 = (const float*)d_in[6];
  const float* b2 = (const float*)d_in[7];
  float* out = (float*)d_out;

  const int N = in_sizes[0] / C_DIM;
  const int totalW = K_DIM * C_DIM * C_DIM;
  const int SMEM_BYTES = 49152 + 24576 + 1024;   // 74752 -> 2 blocks/CU

  char* ws = (char*)d_ws;
  size_t off = 0;
  auto alloc = [&](size_t bytes) {
    void* p = ws + off;
    off = (off + bytes + 255) & ~(size_t)255;
    return p;
  };
  unsigned short* Wt1 = (unsigned short*)alloc((size_t)totalW * 2);
  unsigned short* Wt2 = (unsigned short*)alloc((size_t)totalW * 2);
  float* stats = (float*)alloc(512 * 4);   // [0:256) conv1, [256:512) conv2
  float* ss1   = (float*)alloc(256 * 4);
  float* ss2   = (float*)alloc(256 * 4);
  int* nbrT    = (int*)alloc((size_t)N * K_DIM * 4);
  unsigned short* y1 = (unsigned short*)alloc((size_t)N * C_DIM * 2);
  unsigned short* xb_ws = (unsigned short*)alloc((size_t)N * C_DIM * 2);
  // fall back to d_out's storage for the bf16 x copy if ws is too small
  unsigned short* xb = (off <= ws_size) ? xb_ws : (unsigned short*)d_out;

  (void)hipFuncSetAttribute((const void*)conv_kernel<0>,
      hipFuncAttributeMaxDynamicSharedMemorySize, SMEM_BYTES);
  (void)hipFuncSetAttribute((const void*)conv_kernel<1>,
      hipFuncAttributeMaxDynamicSharedMemorySize, SMEM_BYTES);

  const int nblk = (N + 255) / 256;
  const float invN = 1.0f / (float)N;

  prep_kernel<<<(totalW + 255) / 256, 256, 0, stream>>>(W1, W2, Wt1, Wt2, stats, 512);
  tr_kernel<<<(N + 63) / 64, 256, 0, stream>>>(nbr, nbrT, N);

  {
    int t4 = N * C_DIM / 4;
    cvt_x_kernel<<<(t4 + 255) / 256, 256, 0, stream>>>(x, xb, t4);
  }

  conv_kernel<0><<<nblk, 512, SMEM_BYTES, stream>>>(xb, nbrT, Wt1, y1, stats, N);
  finalize_kernel<<<1, 128, 0, stream>>>(stats, g1, b1, ss1, invN);

  {
    int t8 = N * C_DIM / 8;
    apply_kernel<<<(t8 + 255) / 256, 256, 0, stream>>>(y1, ss1, t8);
  }

  conv_kernel<1><<<nblk, 512, SMEM_BYTES, stream>>>(y1, nbrT, Wt2, out, stats + 256, N);
  finalize_kernel<<<1, 128, 0, stream>>>(stats + 256, g2, b2, ss2, invN);

  {
    int t4 = N * C_DIM / 4;
    final_kernel<<<(t4 + 255) / 256, 256, 0, stream>>>(out, x, ss2, t4);
  }
}